// Round 2
// baseline (247.063 us; speedup 1.0000x reference)
//
#include <hip/hip_runtime.h>
#include <hip/hip_fp16.h>

#define S_LEN    1024
#define B_SZ     8
#define D_IN     64
#define D_OUT    96
#define NB       8
#define SPAD     100   // padded row stride (floats) for per-batch LDS buffers
#define HPAD     104   // padded row stride (halves) for W tile: rows at word-bank 20i mod 32 -> conflict-free
#define NTHREADS 256
#define EPT      36    // (96*96)/256 W-elements per thread

// LayerNorm over 96 features for 8 rows, in place. tid>>5 = row, tid&31 = lane.
__device__ __forceinline__ void block_layernorm(float* __restrict__ buf,
                                                const float* __restrict__ gamma,
                                                const float* __restrict__ beta,
                                                int tid) {
    const int b = tid >> 5;
    const int r = tid & 31;
    float* row = buf + b * SPAD;
    float v0 = row[r], v1 = row[r + 32], v2 = row[r + 64];
    float sum = v0 + v1 + v2;
    float sq  = fmaf(v0, v0, fmaf(v1, v1, v2 * v2));
    #pragma unroll
    for (int off = 16; off > 0; off >>= 1) {
        sum += __shfl_down(sum, off, 32);
        sq  += __shfl_down(sq,  off, 32);
    }
    sum = __shfl(sum, 0, 32);
    sq  = __shfl(sq,  0, 32);
    const float mu  = sum * (1.0f / 96.0f);
    const float var = fmaf(sq, 1.0f / 96.0f, -(mu * mu));
    const float rs  = rsqrtf(var + 1e-5f);
    row[r]      = fmaf((v0 - mu) * rs, gamma[r],      beta[r]);
    row[r + 32] = fmaf((v1 - mu) * rs, gamma[r + 32], beta[r + 32]);
    row[r + 64] = fmaf((v2 - mu) * rs, gamma[r + 64], beta[r + 64]);
}

// Nk: acc = sum_j xn[b,j] * W[i,j], W stored as f16 in LDS (HPAD stride).
__device__ __forceinline__ float nk_dot(const __half* __restrict__ wrow,
                                        const float* __restrict__ xr) {
    float acc = 0.0f;
    #pragma unroll
    for (int j = 0; j < D_OUT / 8; ++j) {
        float4 raw = *(const float4*)(wrow + 8 * j);   // 8 halves
        const __half2* hp = (const __half2*)&raw;
        float2 c0 = __half22float2(hp[0]);
        float2 c1 = __half22float2(hp[1]);
        float2 c2 = __half22float2(hp[2]);
        float2 c3 = __half22float2(hp[3]);
        float4 xv0 = *(const float4*)(xr + 8 * j);
        float4 xv1 = *(const float4*)(xr + 8 * j + 4);
        acc = fmaf(c0.x, xv0.x, acc); acc = fmaf(c0.y, xv0.y, acc);
        acc = fmaf(c1.x, xv0.z, acc); acc = fmaf(c1.y, xv0.w, acc);
        acc = fmaf(c2.x, xv1.x, acc); acc = fmaf(c2.y, xv1.y, acc);
        acc = fmaf(c3.x, xv1.z, acc); acc = fmaf(c3.y, xv1.w, acc);
    }
    return acc;
}

__global__ void __launch_bounds__(NTHREADS, 4)
hier_fused(const float* __restrict__ seq,  const float* __restrict__ M1,
           const float* __restrict__ P1,   const float* __restrict__ Wres1,
           const float* __restrict__ g1,   const float* __restrict__ b1,
           const float* __restrict__ M2,   const float* __restrict__ P2,
           const float* __restrict__ g2,   const float* __restrict__ b2,
           float* __restrict__ out) {
    // LDS: 19968 (wh) + 3*3200 = 29568 B -> 4 blocks/CU (VGPR-capped), zero tail
    __shared__ __align__(16) __half wh[D_OUT * HPAD];
    __shared__ __align__(16) float xin[B_SZ * SPAD];
    __shared__ __align__(16) float xn [B_SZ * SPAD];
    __shared__ __align__(16) float x1b[B_SZ * SPAD];

    const int s   = blockIdx.x;
    const int tid = threadIdx.x;
    const float sf = (float)s;

    // Load the 8 input rows for this s (8 x 64 floats)
    for (int idx = tid; idx < B_SZ * D_IN; idx += NTHREADS) {
        int b = idx >> 6, k = idx & (D_IN - 1);
        xin[b * SPAD + k] = seq[(b * S_LEN + s) * D_IN + k];
    }

    // phi is layer-independent: compute each cos ONCE, accumulate into both
    // W1 (-> LDS f16) and W2 (-> 36 registers). Halves trans-pipe work.
    float w2r[EPT];
    #pragma unroll
    for (int it = 0; it < EPT; ++it) {
        const int e = tid + it * NTHREADS;
        float p1l[8], p2l[8];
        *(float4*)(&p1l[0]) = *(const float4*)(P1 + e * NB);
        *(float4*)(&p1l[4]) = *(const float4*)(P1 + e * NB + 4);
        *(float4*)(&p2l[0]) = *(const float4*)(P2 + e * NB);
        *(float4*)(&p2l[4]) = *(const float4*)(P2 + e * NB + 4);
        float a1 = 0.0f, a2 = 0.0f;
        #pragma unroll
        for (int g = 0; g < NB; ++g) {
            // period = e*8 + g + 2; v_cos takes revolutions, so no 2*pi mul.
            float pf = (float)(e * NB + 2 + g);
            float v  = sf * __builtin_amdgcn_rcpf(pf);
            v -= floorf(v);
            float c = __builtin_amdgcn_cosf(v);
            a1 = fmaf(p1l[g], c, a1);
            a2 = fmaf(p2l[g], c, a2);
        }
        const int i = e / D_OUT, j = e - i * D_OUT;
        wh[i * HPAD + j] = __float2half(a1);
        w2r[it] = a2;
    }
    __syncthreads();

    // ---- Layer 1: xt1 = x @ M1^T, residual = x @ Wres1^T ----
    for (int idx = tid; idx < B_SZ * D_OUT; idx += NTHREADS) {
        int i = idx >> 3, b = idx & 7;
        const float4* m  = (const float4*)(M1 + i * D_IN);
        const float4* wr = (const float4*)(Wres1 + i * D_IN);
        const float*  xr = xin + b * SPAD;
        float at = 0.0f, ar = 0.0f;
        #pragma unroll
        for (int k = 0; k < D_IN / 4; ++k) {
            float4 mv = m[k], rv = wr[k];
            float x0 = xr[4*k], x1 = xr[4*k+1], x2 = xr[4*k+2], x3 = xr[4*k+3];
            at = fmaf(mv.x, x0, fmaf(mv.y, x1, fmaf(mv.z, x2, fmaf(mv.w, x3, at))));
            ar = fmaf(rv.x, x0, fmaf(rv.y, x1, fmaf(rv.z, x2, fmaf(rv.w, x3, ar))));
        }
        xn [b * SPAD + i] = at;  // pre-norm xt1
        x1b[b * SPAD + i] = ar;  // residual
    }
    __syncthreads();

    block_layernorm(xn, g1, b1, tid);
    __syncthreads();

    // Nk1 + residual -> x1b   (W1 from LDS f16)
    for (int idx = tid; idx < B_SZ * D_OUT; idx += NTHREADS) {
        int i = idx >> 3, b = idx & 7;
        x1b[b * SPAD + i] += nk_dot(wh + i * HPAD, xn + b * SPAD);
    }
    __syncthreads();  // all reads of W1 and writes of x1b complete

    // W2 registers -> LDS (overwrite W1)
    #pragma unroll
    for (int it = 0; it < EPT; ++it) {
        const int e = tid + it * NTHREADS;
        const int i = e / D_OUT, j = e - i * D_OUT;
        wh[i * HPAD + j] = __float2half(w2r[it]);
    }

    // ---- Layer 2: xt2 = x1 @ M2^T ---- (doesn't touch wh; same sync covers both)
    for (int idx = tid; idx < B_SZ * D_OUT; idx += NTHREADS) {
        int i = idx >> 3, b = idx & 7;
        const float4* m  = (const float4*)(M2 + i * D_OUT);
        const float*  xr = x1b + b * SPAD;
        float at = 0.0f;
        #pragma unroll
        for (int k = 0; k < D_OUT / 4; ++k) {
            float4 mv = m[k];
            at = fmaf(mv.x, xr[4*k], fmaf(mv.y, xr[4*k+1],
                 fmaf(mv.z, xr[4*k+2], fmaf(mv.w, xr[4*k+3], at))));
        }
        xn[b * SPAD + i] = at;
    }
    __syncthreads();

    block_layernorm(xn, g2, b2, tid);
    __syncthreads();

    // Nk2 + identity residual -> out
    for (int idx = tid; idx < B_SZ * D_OUT; idx += NTHREADS) {
        int i = idx >> 3, b = idx & 7;
        float acc = nk_dot(wh + i * HPAD, xn + b * SPAD);
        out[(b * S_LEN + s) * D_OUT + i] = acc + x1b[b * SPAD + i];
    }
}

extern "C" void kernel_launch(void* const* d_in, const int* in_sizes, int n_in,
                              void* d_out, int out_size, void* d_ws, size_t ws_size,
                              hipStream_t stream) {
    const float* seq   = (const float*)d_in[0];
    const float* M1    = (const float*)d_in[1];
    const float* P1    = (const float*)d_in[2];
    const float* Wres1 = (const float*)d_in[3];
    const float* g1    = (const float*)d_in[4];
    const float* b1    = (const float*)d_in[5];
    const float* M2    = (const float*)d_in[6];
    const float* P2    = (const float*)d_in[7];
    const float* g2    = (const float*)d_in[8];
    const float* b2    = (const float*)d_in[9];
    float* out = (float*)d_out;

    hier_fused<<<dim3(S_LEN), dim3(NTHREADS), 0, stream>>>(
        seq, M1, P1, Wres1, g1, b1, M2, P2, g2, b2, out);
}

// Round 3
// 128.898 us; speedup vs baseline: 1.9167x; 1.9167x over previous
//
#include <hip/hip_runtime.h>
#include <hip/hip_fp16.h>

#define S_LEN    1024
#define B_SZ     8
#define D_IN     64
#define D_OUT    96
#define NB       8
#define NE       (D_OUT * D_OUT)     // 9216 elements per layer
#define CHUNK    32                  // s-steps per recurrence chain
#define NCHUNK   (S_LEN / CHUNK)     // 32
#define SPAD     100                 // padded row stride (floats), 96-wide rows
#define XPAD     68                  // padded row stride (floats), 64-wide rows
#define HPAD     104                 // padded row stride (halves) for W tile
#define NTHREADS 256

__device__ __forceinline__ float cos_rev(float v) {   // cos(2*pi*v), v in revolutions
    v -= floorf(v);
    return __builtin_amdgcn_cosf(v);
}

// ---------------- Kernel 1: materialize W1, W2 (f16) for all s ----------------
// c(s+1) = 2cos(2pi/p) * c(s) - c(s-1).  One thread owns one element e
// (8 chains in registers).  Exact integer reduction for the chunk's initial
// values; 32-step chunks keep coefficient drift ~1e-4.
__global__ void __launch_bounds__(NTHREADS)
w_kernel(const float* __restrict__ P1, const float* __restrict__ P2,
         __half* __restrict__ W1, __half* __restrict__ W2) {
    const int c  = blockIdx.x / (NE / NTHREADS);   // 36 blocks per s-chunk
    const int eb = blockIdx.x % (NE / NTHREADS);
    const int e  = eb * NTHREADS + threadIdx.x;
    const int s0 = c * CHUNK;

    float p1l[NB], p2l[NB];
    *(float4*)&p1l[0] = *(const float4*)(P1 + e * NB);
    *(float4*)&p1l[4] = *(const float4*)(P1 + e * NB + 4);
    *(float4*)&p2l[0] = *(const float4*)(P2 + e * NB);
    *(float4*)&p2l[4] = *(const float4*)(P2 + e * NB + 4);

    float cc[NB], cp[NB], kk[NB];
    #pragma unroll
    for (int g = 0; g < NB; ++g) {
        const int per   = e * NB + 2 + g;
        const float inv = __builtin_amdgcn_rcpf((float)per);
        const int r     = s0 % per;              // exact reduction (once per chunk)
        cc[g] = cos_rev((float)r * inv);         // c(s0)
        cp[g] = cos_rev((float)(r - 1) * inv);   // c(s0-1), cos even so r-1=-1 ok
        kk[g] = 2.0f * __builtin_amdgcn_cosf(inv);  // 2cos(2pi/p), inv <= 0.5
    }

    #pragma unroll 4
    for (int s = s0; s < s0 + CHUNK; ++s) {
        float a1 = 0.0f, a2 = 0.0f;
        #pragma unroll
        for (int g = 0; g < NB; ++g) {
            a1 = fmaf(p1l[g], cc[g], a1);
            a2 = fmaf(p2l[g], cc[g], a2);
        }
        W1[s * NE + e] = __float2half(a1);   // lanes consecutive e -> coalesced
        W2[s * NE + e] = __float2half(a2);
        #pragma unroll
        for (int g = 0; g < NB; ++g) {
            float cn = fmaf(kk[g], cc[g], -cp[g]);
            cp[g] = cc[g];
            cc[g] = cn;
        }
    }
}

// ---------------- shared helpers ----------------
__device__ __forceinline__ void block_layernorm(float* __restrict__ buf,
                                                const float* __restrict__ gamma,
                                                const float* __restrict__ beta,
                                                int tid) {
    const int b = tid >> 5;
    const int r = tid & 31;
    float* row = buf + b * SPAD;
    float v0 = row[r], v1 = row[r + 32], v2 = row[r + 64];
    float sum = v0 + v1 + v2;
    float sq  = fmaf(v0, v0, fmaf(v1, v1, v2 * v2));
    #pragma unroll
    for (int off = 16; off > 0; off >>= 1) {
        sum += __shfl_down(sum, off, 32);
        sq  += __shfl_down(sq,  off, 32);
    }
    sum = __shfl(sum, 0, 32);
    sq  = __shfl(sq,  0, 32);
    const float mu  = sum * (1.0f / 96.0f);
    const float var = fmaf(sq, 1.0f / 96.0f, -(mu * mu));
    const float rs  = rsqrtf(var + 1e-5f);
    row[r]      = fmaf((v0 - mu) * rs, gamma[r],      beta[r]);
    row[r + 32] = fmaf((v1 - mu) * rs, gamma[r + 32], beta[r + 32]);
    row[r + 64] = fmaf((v2 - mu) * rs, gamma[r + 64], beta[r + 64]);
}

__device__ __forceinline__ float nk_dot(const __half* __restrict__ wrow,
                                        const float* __restrict__ xr) {
    float acc = 0.0f;
    #pragma unroll
    for (int j = 0; j < D_OUT / 8; ++j) {
        float4 raw = *(const float4*)(wrow + 8 * j);   // 8 halves
        const __half2* hp = (const __half2*)&raw;
        float2 c0 = __half22float2(hp[0]);
        float2 c1 = __half22float2(hp[1]);
        float2 c2 = __half22float2(hp[2]);
        float2 c3 = __half22float2(hp[3]);
        float4 xv0 = *(const float4*)(xr + 8 * j);
        float4 xv1 = *(const float4*)(xr + 8 * j + 4);
        acc = fmaf(c0.x, xv0.x, acc); acc = fmaf(c0.y, xv0.y, acc);
        acc = fmaf(c1.x, xv0.z, acc); acc = fmaf(c1.y, xv0.w, acc);
        acc = fmaf(c2.x, xv1.x, acc); acc = fmaf(c2.y, xv1.y, acc);
        acc = fmaf(c3.x, xv1.z, acc); acc = fmaf(c3.y, xv1.w, acc);
    }
    return acc;
}

// Stage one s-slice of W (9216 f16) from global into padded LDS tile.
// 96-half rows = 12 aligned 8-half chunks -> float4 copies, fully coalesced.
__device__ __forceinline__ void stage_W(__half* __restrict__ wh,
                                        const __half* __restrict__ Wg,
                                        int tid) {
    for (int cidx = tid; cidx < NE / 8; cidx += NTHREADS) {   // 1152 chunks
        const int i = cidx / 12;
        const int j = (cidx % 12) * 8;
        *(float4*)(wh + i * HPAD + j) = *(const float4*)(Wg + cidx * 8);
    }
}

// ---------------- Kernel 2: main fused pipeline, W from global ----------------
__global__ void __launch_bounds__(NTHREADS)
hier_main(const float* __restrict__ seq,  const float* __restrict__ M1,
          const float* __restrict__ Wres1, const float* __restrict__ g1,
          const float* __restrict__ b1,   const float* __restrict__ M2,
          const float* __restrict__ g2,   const float* __restrict__ b2,
          const __half* __restrict__ W1g, const __half* __restrict__ W2g,
          float* __restrict__ out) {
    // LDS: 19968 + 2176 + 3200 + 3200 = 28544 B -> 5 blocks/CU
    __shared__ __align__(16) __half wh [D_OUT * HPAD];
    __shared__ __align__(16) float xin[B_SZ * XPAD];
    __shared__ __align__(16) float xn [B_SZ * SPAD];
    __shared__ __align__(16) float x1b[B_SZ * SPAD];

    const int s   = blockIdx.x;
    const int tid = threadIdx.x;

    for (int idx = tid; idx < B_SZ * D_IN; idx += NTHREADS) {
        int b = idx >> 6, k = idx & (D_IN - 1);
        xin[b * XPAD + k] = seq[(b * S_LEN + s) * D_IN + k];
    }
    stage_W(wh, W1g + (size_t)s * NE, tid);
    __syncthreads();

    // Layer 1 GEMV: xt1 = x @ M1^T, residual = x @ Wres1^T
    for (int idx = tid; idx < B_SZ * D_OUT; idx += NTHREADS) {
        int i = idx >> 3, b = idx & 7;
        const float4* m  = (const float4*)(M1 + i * D_IN);
        const float4* wr = (const float4*)(Wres1 + i * D_IN);
        const float*  xr = xin + b * XPAD;
        float at = 0.0f, ar = 0.0f;
        #pragma unroll
        for (int k = 0; k < D_IN / 4; ++k) {
            float4 mv = m[k], rv = wr[k];
            float x0 = xr[4*k], x1 = xr[4*k+1], x2 = xr[4*k+2], x3 = xr[4*k+3];
            at = fmaf(mv.x, x0, fmaf(mv.y, x1, fmaf(mv.z, x2, fmaf(mv.w, x3, at))));
            ar = fmaf(rv.x, x0, fmaf(rv.y, x1, fmaf(rv.z, x2, fmaf(rv.w, x3, ar))));
        }
        xn [b * SPAD + i] = at;
        x1b[b * SPAD + i] = ar;
    }
    __syncthreads();

    block_layernorm(xn, g1, b1, tid);
    __syncthreads();

    // Nk1 + residual -> x1b
    for (int idx = tid; idx < B_SZ * D_OUT; idx += NTHREADS) {
        int i = idx >> 3, b = idx & 7;
        x1b[b * SPAD + i] += nk_dot(wh + i * HPAD, xn + b * SPAD);
    }
    __syncthreads();   // W1 reads + x1b writes complete

    stage_W(wh, W2g + (size_t)s * NE, tid);   // overwrite with W2[s]

    // Layer 2 GEMV (doesn't touch wh; same barrier covers both)
    for (int idx = tid; idx < B_SZ * D_OUT; idx += NTHREADS) {
        int i = idx >> 3, b = idx & 7;
        const float4* m  = (const float4*)(M2 + i * D_OUT);
        const float*  xr = x1b + b * SPAD;
        float at = 0.0f;
        #pragma unroll
        for (int k = 0; k < D_OUT / 4; ++k) {
            float4 mv = m[k];
            at = fmaf(mv.x, xr[4*k], fmaf(mv.y, xr[4*k+1],
                 fmaf(mv.z, xr[4*k+2], fmaf(mv.w, xr[4*k+3], at))));
        }
        xn[b * SPAD + i] = at;
    }
    __syncthreads();

    block_layernorm(xn, g2, b2, tid);
    __syncthreads();

    for (int idx = tid; idx < B_SZ * D_OUT; idx += NTHREADS) {
        int i = idx >> 3, b = idx & 7;
        float acc = nk_dot(wh + i * HPAD, xn + b * SPAD);
        out[(b * S_LEN + s) * D_OUT + i] = acc + x1b[b * SPAD + i];
    }
}

// ---------------- Fallback (round-1 proven kernel) if ws too small ----------------
__global__ void __launch_bounds__(NTHREADS)
hier_fallback(const float* __restrict__ seq,  const float* __restrict__ M1,
              const float* __restrict__ P1,   const float* __restrict__ Wres1,
              const float* __restrict__ g1,   const float* __restrict__ b1,
              const float* __restrict__ M2,   const float* __restrict__ P2,
              const float* __restrict__ g2,   const float* __restrict__ b2,
              float* __restrict__ out) {
    __shared__ __align__(16) float w[D_OUT * SPAD];
    __shared__ __align__(16) float xin[B_SZ * XPAD];
    __shared__ __align__(16) float xn [B_SZ * SPAD];
    __shared__ __align__(16) float x1b[B_SZ * SPAD];
    const int s = blockIdx.x, tid = threadIdx.x;
    const float sf = (float)s;

    for (int idx = tid; idx < B_SZ * D_IN; idx += NTHREADS) {
        int b = idx >> 6, k = idx & (D_IN - 1);
        xin[b * XPAD + k] = seq[(b * S_LEN + s) * D_IN + k];
    }
    for (int e = tid; e < NE; e += NTHREADS) {
        float pl[8];
        *(float4*)&pl[0] = *(const float4*)(P1 + e * NB);
        *(float4*)&pl[4] = *(const float4*)(P1 + e * NB + 4);
        float acc = 0.0f;
        #pragma unroll
        for (int g = 0; g < NB; ++g) {
            float v = sf * __builtin_amdgcn_rcpf((float)(e * NB + 2 + g));
            acc = fmaf(pl[g], cos_rev(v), acc);
        }
        int i = e / D_OUT;
        w[e + (SPAD - D_OUT) * i] = acc;
    }
    __syncthreads();
    for (int idx = tid; idx < B_SZ * D_OUT; idx += NTHREADS) {
        int i = idx >> 3, b = idx & 7;
        const float4* m  = (const float4*)(M1 + i * D_IN);
        const float4* wr = (const float4*)(Wres1 + i * D_IN);
        const float*  xr = xin + b * XPAD;
        float at = 0.0f, ar = 0.0f;
        #pragma unroll
        for (int k = 0; k < D_IN / 4; ++k) {
            float4 mv = m[k], rv = wr[k];
            float x0 = xr[4*k], x1 = xr[4*k+1], x2 = xr[4*k+2], x3 = xr[4*k+3];
            at = fmaf(mv.x, x0, fmaf(mv.y, x1, fmaf(mv.z, x2, fmaf(mv.w, x3, at))));
            ar = fmaf(rv.x, x0, fmaf(rv.y, x1, fmaf(rv.z, x2, fmaf(rv.w, x3, ar))));
        }
        xn [b * SPAD + i] = at;
        x1b[b * SPAD + i] = ar;
    }
    __syncthreads();
    block_layernorm(xn, g1, b1, tid);
    __syncthreads();
    for (int idx = tid; idx < B_SZ * D_OUT; idx += NTHREADS) {
        int i = idx >> 3, b = idx & 7;
        const float* wrow = w + i * SPAD;
        const float* xr   = xn + b * SPAD;
        float acc = 0.0f;
        #pragma unroll
        for (int j = 0; j < D_OUT / 4; ++j) {
            float4 wv = *(const float4*)(wrow + 4 * j);
            float4 xv = *(const float4*)(xr + 4 * j);
            acc = fmaf(wv.x, xv.x, fmaf(wv.y, xv.y, fmaf(wv.z, xv.z, fmaf(wv.w, xv.w, acc))));
        }
        x1b[b * SPAD + i] += acc;
    }
    __syncthreads();
    for (int e = tid; e < NE; e += NTHREADS) {
        float pl[8];
        *(float4*)&pl[0] = *(const float4*)(P2 + e * NB);
        *(float4*)&pl[4] = *(const float4*)(P2 + e * NB + 4);
        float acc = 0.0f;
        #pragma unroll
        for (int g = 0; g < NB; ++g) {
            float v = sf * __builtin_amdgcn_rcpf((float)(e * NB + 2 + g));
            acc = fmaf(pl[g], cos_rev(v), acc);
        }
        int i = e / D_OUT;
        w[e + (SPAD - D_OUT) * i] = acc;
    }
    for (int idx = tid; idx < B_SZ * D_OUT; idx += NTHREADS) {
        int i = idx >> 3, b = idx & 7;
        const float4* m  = (const float4*)(M2 + i * D_OUT);
        const float*  xr = x1b + b * SPAD;
        float at = 0.0f;
        #pragma unroll
        for (int k = 0; k < D_OUT / 4; ++k) {
            float4 mv = m[k];
            at = fmaf(mv.x, xr[4*k], fmaf(mv.y, xr[4*k+1],
                 fmaf(mv.z, xr[4*k+2], fmaf(mv.w, xr[4*k+3], at))));
        }
        xn[b * SPAD + i] = at;
    }
    __syncthreads();
    block_layernorm(xn, g2, b2, tid);
    __syncthreads();
    for (int idx = tid; idx < B_SZ * D_OUT; idx += NTHREADS) {
        int i = idx >> 3, b = idx & 7;
        const float* wrow = w + i * SPAD;
        const float* xr   = xn + b * SPAD;
        float acc = 0.0f;
        #pragma unroll
        for (int j = 0; j < D_OUT / 4; ++j) {
            float4 wv = *(const float4*)(wrow + 4 * j);
            float4 xv = *(const float4*)(xr + 4 * j);
            acc = fmaf(wv.x, xv.x, fmaf(wv.y, xv.y, fmaf(wv.z, xv.z, fmaf(wv.w, xv.w, acc))));
        }
        out[(b * S_LEN + s) * D_OUT + i] = acc + x1b[b * SPAD + i];
    }
}

extern "C" void kernel_launch(void* const* d_in, const int* in_sizes, int n_in,
                              void* d_out, int out_size, void* d_ws, size_t ws_size,
                              hipStream_t stream) {
    const float* seq   = (const float*)d_in[0];
    const float* M1    = (const float*)d_in[1];
    const float* P1    = (const float*)d_in[2];
    const float* Wres1 = (const float*)d_in[3];
    const float* g1    = (const float*)d_in[4];
    const float* b1    = (const float*)d_in[5];
    const float* M2    = (const float*)d_in[6];
    const float* P2    = (const float*)d_in[7];
    const float* g2    = (const float*)d_in[8];
    const float* b2    = (const float*)d_in[9];
    float* out = (float*)d_out;

    const size_t need = (size_t)2 * S_LEN * NE * sizeof(__half);   // 37.75 MB
    if (ws_size >= need) {
        __half* W1 = (__half*)d_ws;
        __half* W2 = W1 + (size_t)S_LEN * NE;
        w_kernel<<<dim3(NCHUNK * (NE / NTHREADS)), dim3(NTHREADS), 0, stream>>>(P1, P2, W1, W2);
        hier_main<<<dim3(S_LEN), dim3(NTHREADS), 0, stream>>>(
            seq, M1, Wres1, g1, b1, M2, g2, b2, W1, W2, out);
    } else {
        hier_fallback<<<dim3(S_LEN), dim3(NTHREADS), 0, stream>>>(
            seq, M1, P1, Wres1, g1, b1, M2, P2, g2, b2, out);
    }
}